// Round 7
// baseline (301.218 us; speedup 1.0000x reference)
//
#include <hip/hip_runtime.h>
#include <cmath>

#define WAVE 64
#define TPB  256
#define JPB  128    // broadcast extent (columns/rows) per block

__device__ __forceinline__ float fastrcp(float x) { return __builtin_amdgcn_rcpf(x); }

__device__ __forceinline__ unsigned sortable_u32(float f) {
    unsigned b = __float_as_uint(f);
    return (b & 0x80000000u) ? ~b : (b | 0x80000000u);
}

// mask may arrive as u8 bool, i32, or f32 — probe byte pattern.
__device__ __forceinline__ int mask_mode(const void* maskp) {
    const unsigned char* mb = (const unsigned char*)maskp;
    unsigned char b0 = mb[0], b1 = mb[1];
    if (b0 != 0 && b1 != 0) return 0;   // u8
    if (b0 != 0) return 1;              // i32
    return 2;                           // f32
}
__device__ __forceinline__ float mask_v(const void* maskp, int t, int mode) {
    if (mode == 0) return ((const unsigned char*)maskp)[t] ? 1.0f : 0.0f;
    if (mode == 1) return ((const int*)maskp)[t] ? 1.0f : 0.0f;
    return (((const float*)maskp)[t] != 0.0f) ? 1.0f : 0.0f;
}
__device__ __forceinline__ int midx(int m, int nsh, int N) {
    return (nsh >= 0) ? (m >> nsh) : (m / N);
}

__device__ __forceinline__ double wave_sum_d(double x) {
    for (int off = 32; off >= 1; off >>= 1) x += __shfl_xor(x, off);
    return x;
}

// ---------------------------------------------------------------------------
// ONE kernel. Two lane-local roles split by blockIdx (no LDS / shuffles /
// atomics in hot loops; broadcast side via blockIdx-uniform scalar loads,
// conversions recomputed inline). Partials to ws. Last block to finish
// (device-scope counter) combines partials and computes both losses.
// h = giou + 1 (exact correction applied in f64 at the end).
// ---------------------------------------------------------------------------
__global__ __launch_bounds__(TPB) void fused_kernel(
        const float4* __restrict__ pred, const float4* __restrict__ tgt,
        const void* __restrict__ maskp, int M, int nsh, int N,
        int RB, int CPR,
        unsigned long long* __restrict__ keypart, float* __restrict__ colpart,
        int* __restrict__ idxw, float* __restrict__ colsumhw,
        unsigned int* __restrict__ counter, float* __restrict__ out) {
    const int tid  = threadIdx.x;
    const int lane = tid & (WAVE - 1);
    const int mode = mask_mode(maskp);

    if ((int)blockIdx.x < RB) {
        // ---- rows-role: 256 lane-resident tgt rows x JPB broadcast pred cols
        const int rb = blockIdx.x / CPR;
        const int cj = blockIdx.x % CPR;          // uniform column macro-chunk
        const int r  = rb * TPB + tid;
        float4 a  = tgt[r];
        float  aA = (a.z - a.x) * (a.w - a.y);
        unsigned long long cm0 = __ballot(mask_v(maskp, midx(cj * JPB + lane, nsh, N), mode) > 0.0f);
        unsigned long long cm1 = __ballot(mask_v(maskp, midx(cj * JPB + 64 + lane, nsh, N), mode) > 0.0f);
        const float4* __restrict__ pc = pred + (size_t)cj * JPB;   // block-uniform

        float best = -INFINITY;
        int   bidx = 0;
#pragma unroll 8
        for (int j = 0; j < JPB; ++j) {
            unsigned long long bit = (j < 64) ? (cm0 >> j) : (cm1 >> (j - 64));
            if (!(bit & 1ull)) continue;                 // uniform scalar skip
            float4 p  = pc[j];                           // s_load (broadcast)
            float bx1 = fmaf(-0.5f, p.z, p.x), by1 = fmaf(-0.5f, p.w, p.y);
            float bx2 = fmaf( 0.5f, p.z, p.x), by2 = fmaf( 0.5f, p.w, p.y);
            float aB  = (bx2 - bx1) * (by2 - by1);       // faithful to reference
            float ltx = fmaxf(a.x, bx1), lty = fmaxf(a.y, by1);
            float rbx = fminf(a.z, bx2), rby = fminf(a.w, by2);
            float w = fmaxf(rbx - ltx, 0.0f), h = fmaxf(rby - lty, 0.0f);
            float inter = w * h;
            float uni = aA + aB - inter;
            float cx1 = fminf(a.x, bx1), cy1 = fminf(a.y, by1);
            float cx2 = fmaxf(a.z, bx2), cy2 = fmaxf(a.w, by2);
            float areaC = (cx2 - cx1) * (cy2 - cy1);     // >= 0 by construction
            float hval = fmaf(uni, fastrcp(areaC), inter * fastrcp(uni));
            if (hval > best) { best = hval; bidx = cj * JPB + j; } // strict >, asc j
        }
        keypart[(size_t)cj * M + r] = ((unsigned long long)sortable_u32(best) << 32)
                                    | (unsigned)(~bidx);
    } else {
        // ---- cols-role: 256 lane-resident pred cols x JPB broadcast tgt rows
        const int b2 = blockIdx.x - RB;
        const int cb = b2 / CPR;
        const int rj = b2 % CPR;                  // uniform row macro-chunk
        const int c  = cb * TPB + tid;
        float4 p  = pred[c];
        float bx1 = fmaf(-0.5f, p.z, p.x), by1 = fmaf(-0.5f, p.w, p.y);
        float bx2 = fmaf( 0.5f, p.z, p.x), by2 = fmaf( 0.5f, p.w, p.y);
        float aB  = (bx2 - bx1) * (by2 - by1);
        unsigned long long rm0 = __ballot(mask_v(maskp, midx(rj * JPB + lane, nsh, N), mode) > 0.0f);
        unsigned long long rm1 = __ballot(mask_v(maskp, midx(rj * JPB + 64 + lane, nsh, N), mode) > 0.0f);
        const float4* __restrict__ ar = tgt + (size_t)rj * JPB;    // block-uniform

        float csum = 0.0f;
#pragma unroll 8
        for (int j = 0; j < JPB; ++j) {
            unsigned long long bit = (j < 64) ? (rm0 >> j) : (rm1 >> (j - 64));
            if (!(bit & 1ull)) continue;                 // vi=0 rows skipped
            float4 a  = ar[j];                           // s_load (broadcast)
            float  aA = (a.z - a.x) * (a.w - a.y);
            float ltx = fmaxf(a.x, bx1), lty = fmaxf(a.y, by1);
            float rbx = fminf(a.z, bx2), rby = fminf(a.w, by2);
            float w = fmaxf(rbx - ltx, 0.0f), h = fmaxf(rby - lty, 0.0f);
            float inter = w * h;
            float uni = aA + aB - inter;
            float cx1 = fminf(a.x, bx1), cy1 = fminf(a.y, by1);
            float cx2 = fmaxf(a.z, bx2), cy2 = fmaxf(a.w, by2);
            float areaC = (cx2 - cx1) * (cy2 - cy1);
            float hval = fmaf(uni, fastrcp(areaC), inter * fastrcp(uni));
            csum += hval;                                // vi==1 when bit set
        }
        colpart[(size_t)rj * M + c] = csum;
    }

    // ---- last-block-done: combine partials + finalize ----------------------
    __shared__ int lastflag;
    __threadfence();                                 // publish partials (device)
    __syncthreads();
    if (tid == 0) {
        unsigned old = atomicAdd(counter, 1u);       // device-scope
        lastflag = (old == gridDim.x - 1) ? 1 : 0;
    }
    __syncthreads();
    if (!lastflag) return;
    __threadfence();                                 // acquire all partials

    // phase A: reduce 2*CPR partials per element -> idxw / colsumhw (via ws)
    for (int m = tid; m < M; m += TPB) {
        unsigned long long k = keypart[m];
        float s = colpart[m];
        for (int cc = 1; cc < CPR; ++cc) {
            unsigned long long kc = keypart[(size_t)cc * M + m];
            k = (kc > k) ? kc : k;
            s += colpart[(size_t)cc * M + m];
        }
        idxw[m] = (int)(~(unsigned)k);
        colsumhw[m] = s;
    }
    __syncthreads();   // block-local visibility of idxw/colsumhw

    // phase B: f64 scalar reductions
    double sumV = 0.0, S2 = 0.0, S1h = 0.0, bbox = 0.0;
    for (int m = tid; m < M; m += TPB) {
        float vi = mask_v(maskp, midx(m, nsh, N), mode);
        int   k  = idxw[m];
        float vk = mask_v(maskp, midx(k, nsh, N), mode);
        sumV += (double)vi;
        S2   += (double)vk;
        S1h  += (double)vk * (double)colsumhw[k];
        float4 p = pred[k];
        float sx1 = fmaf(-0.5f, p.z, p.x), sy1 = fmaf(-0.5f, p.w, p.y);
        float sx2 = fmaf( 0.5f, p.z, p.x), sy2 = fmaf( 0.5f, p.w, p.y);
        float4 t = tgt[m];
        bbox += (double)vi * (double)(fabsf(sx1 - t.x) + fabsf(sy1 - t.y) +
                                      fabsf(sx2 - t.z) + fabsf(sy2 - t.w));
    }
    __shared__ double red[4 * (TPB / WAVE)];
    sumV = wave_sum_d(sumV);
    S2   = wave_sum_d(S2);
    S1h  = wave_sum_d(S1h);
    bbox = wave_sum_d(bbox);
    int wid = tid >> 6;
    const int NW = TPB / WAVE;
    if (lane == 0) {
        red[wid] = sumV; red[NW + wid] = S2; red[2 * NW + wid] = S1h; red[3 * NW + wid] = bbox;
    }
    __syncthreads();
    if (tid == 0) {
        double a = 0, b = 0, c = 0, d = 0;
        for (int w = 0; w < NW; ++w) {
            a += red[w]; b += red[NW + w]; c += red[2 * NW + w]; d += red[3 * NW + w];
        }
        // colsum_g = colsum_h - sumV  =>  loss_giou = 2 - S1h/(sumV*S2)
        out[0] = (float)(2.0 - c / (a * b));
        out[1] = (float)(d / (4.0 * a));
    }
}

// ---------------------------------------------------------------------------
extern "C" void kernel_launch(void* const* d_in, const int* in_sizes, int n_in,
                              void* d_out, int out_size, void* d_ws, size_t ws_size,
                              hipStream_t stream) {
    const float4* pred = (const float4*)d_in[0];
    const float4* tgt  = (const float4*)d_in[1];
    const void*   mask = d_in[2];

    int M = in_sizes[0] / 4;        // 4096 (B*T*N); multiple of 256
    int N = M / in_sizes[2];        // boxes per mask entry (8)
    int nsh = -1;
    for (int s = 0; s < 31; ++s) if ((1 << s) == N) { nsh = s; break; }

    int CPR = M / JPB;              // macro-chunks per row/col (32)

    char* ws = (char*)d_ws;
    unsigned int* counter = (unsigned int*)ws;             ws += 16;
    unsigned long long* keypart = (unsigned long long*)ws; ws += (size_t)CPR * M * 8;
    float* colpart  = (float*)ws;                          ws += (size_t)CPR * M * 4;
    int*   idxw     = (int*)ws;                            ws += (size_t)M * 4;
    float* colsumhw = (float*)ws;                          ws += (size_t)M * 4;
    float* out = (float*)d_out;

    hipMemsetAsync(counter, 0, 4, stream);

    int RB = (M / TPB) * CPR;       // 512 rows-role blocks
    int CB = RB;                    // 512 cols-role blocks
    fused_kernel<<<RB + CB, TPB, 0, stream>>>(
        pred, tgt, mask, M, nsh, N, RB, CPR,
        keypart, colpart, idxw, colsumhw, counter, out);
}

// Round 8
// 163.335 us; speedup vs baseline: 1.8442x; 1.8442x over previous
//
#include <hip/hip_runtime.h>
#include <cmath>

#define WAVE 64
#define TPB  256
#define FTPB 1024
#define MMAX 4096

__device__ __forceinline__ float fastrcp(float x) { return __builtin_amdgcn_rcpf(x); }

__device__ __forceinline__ unsigned sortable_u32(float f) {
    unsigned b = __float_as_uint(f);
    return (b & 0x80000000u) ? ~b : (b | 0x80000000u);
}

// mask may arrive as u8 bool, i32, or f32 — probe byte pattern.
__device__ __forceinline__ int mask_mode(const void* maskp) {
    const unsigned char* mb = (const unsigned char*)maskp;
    unsigned char b0 = mb[0], b1 = mb[1];
    if (b0 != 0 && b1 != 0) return 0;   // u8
    if (b0 != 0) return 1;              // i32
    return 2;                           // f32
}
__device__ __forceinline__ float mask_v(const void* maskp, int t, int mode) {
    if (mode == 0) return ((const unsigned char*)maskp)[t] ? 1.0f : 0.0f;
    if (mode == 1) return ((const int*)maskp)[t] ? 1.0f : 0.0f;
    return (((const float*)maskp)[t] != 0.0f) ? 1.0f : 0.0f;
}
__device__ __forceinline__ int midx(int m, int nsh, int N) {
    return (nsh >= 0) ? (m >> nsh) : (m / N);
}

// ---------------- prep: pack per-box records (32B):  -----------------------
//   pkS[2m]   = {sx1, sy1, sx2, sy2}   (pred converted to xyxy)
//   pkS[2m+1] = {areaS, v, bias, 0}    bias = v>0 ? 0 : -inf
//   pkT likewise for tgt (already xyxy).
__global__ __launch_bounds__(TPB) void prep_kernel(
        const float4* __restrict__ pred, const float4* __restrict__ tgt,
        const void* __restrict__ maskp, int M, int nsh, int N,
        float4* __restrict__ pkS, float4* __restrict__ pkT) {
    int m = blockIdx.x * blockDim.x + threadIdx.x;
    if (m >= M) return;
    float vm  = mask_v(maskp, midx(m, nsh, N), mask_mode(maskp));
    float bias = (vm > 0.0f) ? 0.0f : -INFINITY;

    float4 p = pred[m];
    float x1 = p.x - 0.5f * p.z, y1 = p.y - 0.5f * p.w;
    float x2 = p.x + 0.5f * p.z, y2 = p.y + 0.5f * p.w;
    pkS[2 * m]     = make_float4(x1, y1, x2, y2);
    pkS[2 * m + 1] = make_float4((x2 - x1) * (y2 - y1), vm, bias, 0.0f);

    float4 t = tgt[m];
    pkT[2 * m]     = t;
    pkT[2 * m + 1] = make_float4((t.z - t.x) * (t.w - t.y), vm, bias, 0.0f);
}

// ---------------------------------------------------------------------------
// Pass: two lane-local roles split by blockIdx. Branchless inner loop:
// broadcast side via blockIdx-uniform s_load_dwordx8 (pipelines freely),
// mask folded in as +bias (argmax) / *v (colsum). h = giou+1 form.
// ---------------------------------------------------------------------------
__global__ __launch_bounds__(TPB) void pass_kernel(
        const float4* __restrict__ pkS, const float4* __restrict__ pkT,
        int M, int RB,
        unsigned long long* __restrict__ keypart, float* __restrict__ colpart) {
    const int C   = M >> 6;                     // 64-wide chunks
    const int tid = threadIdx.x;

    if ((int)blockIdx.x < RB) {
        // rows-role: 256 lane-resident tgt rows x 64 broadcast pred cols
        const int rb = blockIdx.x / C;
        const int cc = blockIdx.x % C;          // uniform chunk
        const int r  = rb * TPB + tid;
        float4 a  = pkT[2 * r];
        float  aA = pkT[2 * r + 1].x;
        const float4* __restrict__ bp = pkS + (size_t)cc * 128;   // block-uniform

        float best = -INFINITY;
        int   bidx = 0;
#pragma unroll 8
        for (int j = 0; j < 64; ++j) {
            float4 b  = bp[2 * j];              // s_load_dwordx8 (broadcast)
            float4 bm = bp[2 * j + 1];          // {aB, v, bias, _}
            float ltx = fmaxf(a.x, b.x), lty = fmaxf(a.y, b.y);
            float rbx = fminf(a.z, b.z), rby = fminf(a.w, b.w);
            float w = fmaxf(rbx - ltx, 0.0f), h = fmaxf(rby - lty, 0.0f);
            float inter = w * h;
            float uni = aA + bm.x - inter;
            float cx1 = fminf(a.x, b.x), cy1 = fminf(a.y, b.y);
            float cx2 = fmaxf(a.z, b.z), cy2 = fmaxf(a.w, b.w);
            float areaC = (cx2 - cx1) * (cy2 - cy1);   // >= 0 by construction
            float hval = fmaf(uni, fastrcp(areaC), inter * fastrcp(uni));
            float val  = hval + bm.z;           // masked col -> -inf
            if (val > best) { best = val; bidx = cc * 64 + j; } // strict >, asc j
        }
        keypart[(size_t)cc * M + r] = ((unsigned long long)sortable_u32(best) << 32)
                                    | (unsigned)(~bidx);
    } else {
        // cols-role: 256 lane-resident pred cols x 64 broadcast tgt rows
        const int b2 = blockIdx.x - RB;
        const int cb = b2 / C;
        const int rc = b2 % C;                  // uniform chunk
        const int c  = cb * TPB + tid;
        float4 b  = pkS[2 * c];
        float  aB = pkS[2 * c + 1].x;
        const float4* __restrict__ ap = pkT + (size_t)rc * 128;   // block-uniform

        float csum = 0.0f;
#pragma unroll 8
        for (int j = 0; j < 64; ++j) {
            float4 a  = ap[2 * j];              // s_load_dwordx8 (broadcast)
            float4 am = ap[2 * j + 1];          // {aA, v, bias, _}
            float ltx = fmaxf(a.x, b.x), lty = fmaxf(a.y, b.y);
            float rbx = fminf(a.z, b.z), rby = fminf(a.w, b.w);
            float w = fmaxf(rbx - ltx, 0.0f), h = fmaxf(rby - lty, 0.0f);
            float inter = w * h;
            float uni = am.x + aB - inter;
            float cx1 = fminf(a.x, b.x), cy1 = fminf(a.y, b.y);
            float cx2 = fmaxf(a.z, b.z), cy2 = fmaxf(a.w, b.w);
            float areaC = (cx2 - cx1) * (cy2 - cy1);
            float hval = fmaf(uni, fastrcp(areaC), inter * fastrcp(uni));
            csum = fmaf(am.y, hval, csum);      // * v (0 or 1)
        }
        colpart[(size_t)rc * M + c] = csum;
    }
}

// ---------------- finalize: combine partials + all reductions, 1 block -----
__device__ __forceinline__ double wave_sum_d(double x) {
    for (int off = 32; off >= 1; off >>= 1) x += __shfl_xor(x, off);
    return x;
}

__global__ __launch_bounds__(FTPB) void finalize_kernel(
        const float4* __restrict__ pkS, const float4* __restrict__ pkT,
        const unsigned long long* __restrict__ keypart,
        const float* __restrict__ colpart, int M, float* __restrict__ out) {
    __shared__ float cs_lds[MMAX];
    __shared__ int   idx_lds[MMAX];
    __shared__ double red[4 * (FTPB / WAVE)];
    const int tid = threadIdx.x;
    const int C = M >> 6;

    // phase A: combine 64 partials per row/col
    for (int m = tid; m < M; m += FTPB) {
        unsigned long long k = keypart[m];
        float s = colpart[m];
        for (int cc = 1; cc < C; ++cc) {
            unsigned long long kc = keypart[(size_t)cc * M + m];
            k = (kc > k) ? kc : k;
            s += colpart[(size_t)cc * M + m];
        }
        idx_lds[m] = (int)(~(unsigned)k);
        cs_lds[m] = s;
    }
    __syncthreads();

    // phase B: f64 scalar reductions
    double sumV = 0.0, S2 = 0.0, S1h = 0.0, bbox = 0.0;
    for (int m = tid; m < M; m += FTPB) {
        float4 tm = pkT[2 * m];         // tgt box
        float  vi = pkT[2 * m + 1].y;
        int    k  = idx_lds[m];
        float4 sk = pkS[2 * k];         // matched converted pred box
        float  vk = pkS[2 * k + 1].y;
        sumV += (double)vi;
        S2   += (double)vk;
        S1h  += (double)vk * (double)cs_lds[k];
        bbox += (double)vi * (double)(fabsf(sk.x - tm.x) + fabsf(sk.y - tm.y) +
                                      fabsf(sk.z - tm.z) + fabsf(sk.w - tm.w));
    }
    sumV = wave_sum_d(sumV);
    S2   = wave_sum_d(S2);
    S1h  = wave_sum_d(S1h);
    bbox = wave_sum_d(bbox);
    int wid = tid >> 6, lane = tid & (WAVE - 1);
    const int NW = FTPB / WAVE;
    if (lane == 0) {
        red[wid] = sumV; red[NW + wid] = S2; red[2 * NW + wid] = S1h; red[3 * NW + wid] = bbox;
    }
    __syncthreads();
    if (tid == 0) {
        double a = 0, b = 0, c = 0, d = 0;
        for (int w = 0; w < NW; ++w) {
            a += red[w]; b += red[NW + w]; c += red[2 * NW + w]; d += red[3 * NW + w];
        }
        // colsum_g = colsum_h - sumV  =>  loss_giou = 2 - S1h/(sumV*S2)
        out[0] = (float)(2.0 - c / (a * b));
        out[1] = (float)(d / (4.0 * a));
    }
}

// ---------------------------------------------------------------------------
extern "C" void kernel_launch(void* const* d_in, const int* in_sizes, int n_in,
                              void* d_out, int out_size, void* d_ws, size_t ws_size,
                              hipStream_t stream) {
    const float4* pred = (const float4*)d_in[0];
    const float4* tgt  = (const float4*)d_in[1];
    const void*   mask = d_in[2];

    int M = in_sizes[0] / 4;        // 4096 (B*T*N); multiple of 256
    int N = M / in_sizes[2];        // boxes per mask entry (8)
    int nsh = -1;
    for (int s = 0; s < 31; ++s) if ((1 << s) == N) { nsh = s; break; }

    int C = M >> 6;                 // 64

    char* ws = (char*)d_ws;
    float4* pkS = (float4*)ws;                             ws += (size_t)M * 32;
    float4* pkT = (float4*)ws;                             ws += (size_t)M * 32;
    unsigned long long* keypart = (unsigned long long*)ws; ws += (size_t)C * M * 8;
    float* colpart = (float*)ws;                           ws += (size_t)C * M * 4;
    float* out = (float*)d_out;

    prep_kernel<<<(M + TPB - 1) / TPB, TPB, 0, stream>>>(
        pred, tgt, mask, M, nsh, N, pkS, pkT);

    int RB = (M / TPB) * C;         // 1024 rows-role blocks
    pass_kernel<<<2 * RB, TPB, 0, stream>>>(pkS, pkT, M, RB, keypart, colpart);

    finalize_kernel<<<1, FTPB, 0, stream>>>(pkS, pkT, keypart, colpart, M, out);
}

// Round 9
// 105.975 us; speedup vs baseline: 2.8423x; 1.5413x over previous
//
#include <hip/hip_runtime.h>
#include <cmath>

#define WAVE 64
#define TPB  256
#define FTPB 1024
#define JPB  128    // broadcast extent per block -> C = M/JPB partials

__device__ __forceinline__ float fastrcp(float x) { return __builtin_amdgcn_rcpf(x); }

__device__ __forceinline__ unsigned sortable_u32(float f) {
    unsigned b = __float_as_uint(f);
    return (b & 0x80000000u) ? ~b : (b | 0x80000000u);
}

// mask may arrive as u8 bool, i32, or f32 — probe byte pattern.
__device__ __forceinline__ int mask_mode(const void* maskp) {
    const unsigned char* mb = (const unsigned char*)maskp;
    unsigned char b0 = mb[0], b1 = mb[1];
    if (b0 != 0 && b1 != 0) return 0;   // u8
    if (b0 != 0) return 1;              // i32
    return 2;                           // f32
}
__device__ __forceinline__ float mask_v(const void* maskp, int t, int mode) {
    if (mode == 0) return ((const unsigned char*)maskp)[t] ? 1.0f : 0.0f;
    if (mode == 1) return ((const int*)maskp)[t] ? 1.0f : 0.0f;
    return (((const float*)maskp)[t] != 0.0f) ? 1.0f : 0.0f;
}
__device__ __forceinline__ int midx(int m, int nsh, int N) {
    return (nsh >= 0) ? (m >> nsh) : (m / N);
}

// ---------------- prep: pack per-box records (32B) -------------------------
//   pk[2m]   = {x1, y1, x2, y2}
//   pk[2m+1] = {area, v, bias, 0}   bias = v>0 ? 0 : -inf
__global__ __launch_bounds__(TPB) void prep_kernel(
        const float4* __restrict__ pred, const float4* __restrict__ tgt,
        const void* __restrict__ maskp, int M, int nsh, int N,
        float4* __restrict__ pkS, float4* __restrict__ pkT) {
    int m = blockIdx.x * blockDim.x + threadIdx.x;
    if (m >= M) return;
    float vm  = mask_v(maskp, midx(m, nsh, N), mask_mode(maskp));
    float bias = (vm > 0.0f) ? 0.0f : -INFINITY;

    float4 p = pred[m];
    float x1 = p.x - 0.5f * p.z, y1 = p.y - 0.5f * p.w;
    float x2 = p.x + 0.5f * p.z, y2 = p.y + 0.5f * p.w;
    pkS[2 * m]     = make_float4(x1, y1, x2, y2);
    pkS[2 * m + 1] = make_float4((x2 - x1) * (y2 - y1), vm, bias, 0.0f);

    float4 t = tgt[m];
    pkT[2 * m]     = t;
    pkT[2 * m + 1] = make_float4((t.z - t.x) * (t.w - t.y), vm, bias, 0.0f);
}

// ---------------------------------------------------------------------------
// Pass: two lane-local roles split by blockIdx. Branchless inner loop:
// broadcast side via blockIdx-uniform scalar loads (pipelines freely),
// mask folded in as +bias (argmax) / *v (colsum). h = giou+1 form.
// ---------------------------------------------------------------------------
__global__ __launch_bounds__(TPB) void pass_kernel(
        const float4* __restrict__ pkS, const float4* __restrict__ pkT,
        int M, int RB,
        unsigned long long* __restrict__ keypart, float* __restrict__ colpart) {
    const int C   = M / JPB;                    // macro-chunks
    const int tid = threadIdx.x;

    if ((int)blockIdx.x < RB) {
        // rows-role: 256 lane-resident tgt rows x JPB broadcast pred cols
        const int rb = blockIdx.x / C;
        const int cc = blockIdx.x % C;          // uniform chunk
        const int r  = rb * TPB + tid;
        float4 a  = pkT[2 * r];
        float  aA = pkT[2 * r + 1].x;
        const float4* __restrict__ bp = pkS + (size_t)cc * (2 * JPB);  // block-uniform

        float best = -INFINITY;
        int   bidx = 0;
#pragma unroll 8
        for (int j = 0; j < JPB; ++j) {
            float4 b  = bp[2 * j];              // scalar broadcast load
            float4 bm = bp[2 * j + 1];          // {aB, v, bias, _}
            float ltx = fmaxf(a.x, b.x), lty = fmaxf(a.y, b.y);
            float rbx = fminf(a.z, b.z), rby = fminf(a.w, b.w);
            float w = fmaxf(rbx - ltx, 0.0f), h = fmaxf(rby - lty, 0.0f);
            float inter = w * h;
            float uni = aA + bm.x - inter;
            float cx1 = fminf(a.x, b.x), cy1 = fminf(a.y, b.y);
            float cx2 = fmaxf(a.z, b.z), cy2 = fmaxf(a.w, b.w);
            float areaC = (cx2 - cx1) * (cy2 - cy1);   // >= 0 by construction
            float hval = fmaf(uni, fastrcp(areaC), inter * fastrcp(uni));
            float val  = hval + bm.z;           // masked col -> -inf
            if (val > best) { best = val; bidx = cc * JPB + j; } // strict >, asc j
        }
        keypart[(size_t)cc * M + r] = ((unsigned long long)sortable_u32(best) << 32)
                                    | (unsigned)(~bidx);
    } else {
        // cols-role: 256 lane-resident pred cols x JPB broadcast tgt rows
        const int b2 = blockIdx.x - RB;
        const int cb = b2 / C;
        const int rc = b2 % C;                  // uniform chunk
        const int c  = cb * TPB + tid;
        float4 b  = pkS[2 * c];
        float  aB = pkS[2 * c + 1].x;
        const float4* __restrict__ ap = pkT + (size_t)rc * (2 * JPB);  // block-uniform

        float csum = 0.0f;
#pragma unroll 8
        for (int j = 0; j < JPB; ++j) {
            float4 a  = ap[2 * j];              // scalar broadcast load
            float4 am = ap[2 * j + 1];          // {aA, v, bias, _}
            float ltx = fmaxf(a.x, b.x), lty = fmaxf(a.y, b.y);
            float rbx = fminf(a.z, b.z), rby = fminf(a.w, b.w);
            float w = fmaxf(rbx - ltx, 0.0f), h = fmaxf(rby - lty, 0.0f);
            float inter = w * h;
            float uni = am.x + aB - inter;
            float cx1 = fminf(a.x, b.x), cy1 = fminf(a.y, b.y);
            float cx2 = fmaxf(a.z, b.z), cy2 = fmaxf(a.w, b.w);
            float areaC = (cx2 - cx1) * (cy2 - cy1);
            float hval = fmaf(uni, fastrcp(areaC), inter * fastrcp(uni));
            csum = fmaf(am.y, hval, csum);      // * v (0 or 1)
        }
        colpart[(size_t)rc * M + c] = csum;
    }
}

// ---------------- wide combine: coalesced, spread across CUs ---------------
__global__ __launch_bounds__(TPB) void reduce_kernel(
        const unsigned long long* __restrict__ keypart,
        const float* __restrict__ colpart, int M, int C,
        int* __restrict__ idx, float* __restrict__ colsumh) {
    int m = blockIdx.x * blockDim.x + threadIdx.x;
    if (m >= M) return;
    unsigned long long k = keypart[m];
    float s = colpart[m];
    for (int cc = 1; cc < C; ++cc) {
        unsigned long long kc = keypart[(size_t)cc * M + m];
        k = (kc > k) ? kc : k;
        s += colpart[(size_t)cc * M + m];
    }
    idx[m] = (int)(~(unsigned)k);
    colsumh[m] = s;
}

// ---------------- finalize: f64 scalar reductions, 1 block -----------------
__device__ __forceinline__ double wave_sum_d(double x) {
    for (int off = 32; off >= 1; off >>= 1) x += __shfl_xor(x, off);
    return x;
}

__global__ __launch_bounds__(FTPB) void finalize_kernel(
        const float4* __restrict__ pkS, const float4* __restrict__ pkT,
        const int* __restrict__ idx, const float* __restrict__ colsumh,
        int M, float* __restrict__ out) {
    __shared__ double red[4 * (FTPB / WAVE)];
    const int tid = threadIdx.x;

    double sumV = 0.0, S2 = 0.0, S1h = 0.0, bbox = 0.0;
    for (int m = tid; m < M; m += FTPB) {
        float4 tm = pkT[2 * m];
        float  vi = pkT[2 * m + 1].y;
        int    k  = idx[m];
        float4 sk = pkS[2 * k];
        float  vk = pkS[2 * k + 1].y;
        sumV += (double)vi;
        S2   += (double)vk;
        S1h  += (double)vk * (double)colsumh[k];
        bbox += (double)vi * (double)(fabsf(sk.x - tm.x) + fabsf(sk.y - tm.y) +
                                      fabsf(sk.z - tm.z) + fabsf(sk.w - tm.w));
    }
    sumV = wave_sum_d(sumV);
    S2   = wave_sum_d(S2);
    S1h  = wave_sum_d(S1h);
    bbox = wave_sum_d(bbox);
    int wid = tid >> 6, lane = tid & (WAVE - 1);
    const int NW = FTPB / WAVE;
    if (lane == 0) {
        red[wid] = sumV; red[NW + wid] = S2; red[2 * NW + wid] = S1h; red[3 * NW + wid] = bbox;
    }
    __syncthreads();
    if (tid == 0) {
        double a = 0, b = 0, c = 0, d = 0;
        for (int w = 0; w < NW; ++w) {
            a += red[w]; b += red[NW + w]; c += red[2 * NW + w]; d += red[3 * NW + w];
        }
        // colsum_g = colsum_h - sumV  =>  loss_giou = 2 - S1h/(sumV*S2)
        out[0] = (float)(2.0 - c / (a * b));
        out[1] = (float)(d / (4.0 * a));
    }
}

// ---------------------------------------------------------------------------
extern "C" void kernel_launch(void* const* d_in, const int* in_sizes, int n_in,
                              void* d_out, int out_size, void* d_ws, size_t ws_size,
                              hipStream_t stream) {
    const float4* pred = (const float4*)d_in[0];
    const float4* tgt  = (const float4*)d_in[1];
    const void*   mask = d_in[2];

    int M = in_sizes[0] / 4;        // 4096 (B*T*N); multiple of 256
    int N = M / in_sizes[2];        // boxes per mask entry (8)
    int nsh = -1;
    for (int s = 0; s < 31; ++s) if ((1 << s) == N) { nsh = s; break; }

    int C = M / JPB;                // 32

    char* ws = (char*)d_ws;
    float4* pkS = (float4*)ws;                             ws += (size_t)M * 32;
    float4* pkT = (float4*)ws;                             ws += (size_t)M * 32;
    unsigned long long* keypart = (unsigned long long*)ws; ws += (size_t)C * M * 8;
    float* colpart = (float*)ws;                           ws += (size_t)C * M * 4;
    int*   idx     = (int*)ws;                             ws += (size_t)M * 4;
    float* colsumh = (float*)ws;                           ws += (size_t)M * 4;
    float* out = (float*)d_out;

    prep_kernel<<<(M + TPB - 1) / TPB, TPB, 0, stream>>>(
        pred, tgt, mask, M, nsh, N, pkS, pkT);

    int RB = (M / TPB) * C;         // 512 rows-role blocks
    pass_kernel<<<2 * RB, TPB, 0, stream>>>(pkS, pkT, M, RB, keypart, colpart);

    reduce_kernel<<<(M + TPB - 1) / TPB, TPB, 0, stream>>>(
        keypart, colpart, M, C, idx, colsumh);

    finalize_kernel<<<1, FTPB, 0, stream>>>(pkS, pkT, idx, colsumh, M, out);
}